// Round 1
// baseline (347.443 us; speedup 1.0000x reference)
//
#include <hip/hip_runtime.h>
#include <hip/hip_bf16.h>
#include <stdint.h>

// Problem constants
#define M_DIM 8192      // 2*4096 flattened batch
#define K_DIM 2048      // ACTIVE (in)
#define N_DIM 2048      // ACTIVE (out)
#define IN_DIM 4096     // ORIG_IN
#define OUT_DIM 4096    // ORIG_OUT
#define SCALING 2.0f    // 32/16

typedef __attribute__((ext_vector_type(8))) short bf16x8_t;  // 8 bf16 = 4 VGPRs
typedef __attribute__((ext_vector_type(4))) float f32x4_t;

__device__ __forceinline__ void load_lds16(const void* gptr, void* lptr) {
    __builtin_amdgcn_global_load_lds(
        (const __attribute__((address_space(1))) uint32_t*)(uintptr_t)gptr,
        (__attribute__((address_space(3))) uint32_t*)(uintptr_t)lptr,
        16, 0, 0);
}

// ---------------------------------------------------------------------------
// Kernel 1: fold LoRA into base weight, cast to bf16.
// ---------------------------------------------------------------------------
__global__ void fold_w_kernel(const float* __restrict__ Wb,
                              const float* __restrict__ lA,   // [16][2048]
                              const float* __restrict__ lB,   // [2048][16]
                              __hip_bfloat16* __restrict__ We) {
    const int k = blockIdx.x * 256 + threadIdx.x;
    const int o = blockIdx.y;
    float acc = Wb[(size_t)o * K_DIM + k];
    #pragma unroll
    for (int r = 0; r < 16; ++r)
        acc += SCALING * lB[o * 16 + r] * lA[r * K_DIM + k];
    We[(size_t)o * K_DIM + k] = __float2bfloat16(acc);
}

// ---------------------------------------------------------------------------
// Kernel 2: gather active input columns + cast to bf16, via LDS staging.
// ---------------------------------------------------------------------------
__global__ void __launch_bounds__(256)
gather_cast_kernel(const float* __restrict__ x,
                   const int* __restrict__ idx,
                   __hip_bfloat16* __restrict__ xs) {
    __shared__ float row[IN_DIM];
    const int n = blockIdx.x;
    const float* xrow = x + (size_t)n * IN_DIM;
    #pragma unroll
    for (int i = 0; i < 4; ++i) {
        const int c = (i * 256 + threadIdx.x) * 4;
        *(float4*)&row[c] = *(const float4*)&xrow[c];
    }
    __syncthreads();
    const int c0 = threadIdx.x * 8;
    int4 i0 = *(const int4*)(idx + c0);
    int4 i1 = *(const int4*)(idx + c0 + 4);
    union { bf16x8_t v; __hip_bfloat16 h[8]; } u;
    u.h[0] = __float2bfloat16(row[i0.x]);
    u.h[1] = __float2bfloat16(row[i0.y]);
    u.h[2] = __float2bfloat16(row[i0.z]);
    u.h[3] = __float2bfloat16(row[i0.w]);
    u.h[4] = __float2bfloat16(row[i1.x]);
    u.h[5] = __float2bfloat16(row[i1.y]);
    u.h[6] = __float2bfloat16(row[i1.z]);
    u.h[7] = __float2bfloat16(row[i1.w]);
    *(bf16x8_t*)(xs + (size_t)n * K_DIM + c0) = u.v;
}

// ---------------------------------------------------------------------------
// Kernel 3: inverse index map. inv[oc] = n such that out_idx[n]==oc, else -1.
// ---------------------------------------------------------------------------
__global__ void build_inv_kernel(const int* __restrict__ oidx,
                                 int* __restrict__ inv) {
    const int c = blockIdx.x * 256 + threadIdx.x;   // 0..4095
    int lo = 0, hi = N_DIM;
    while (lo < hi) {
        const int mid = (lo + hi) >> 1;
        if (oidx[mid] < c) lo = mid + 1; else hi = mid;
    }
    inv[c] = (lo < N_DIM && oidx[lo] == c) ? lo : -1;
}

// ---------------------------------------------------------------------------
// Kernel 4 (new): 256x256 tile GEMM, 8 waves (2Mx4N), BK=32, QUAD-buffered
// LDS (4 x 32KB = 128 KiB).  Counted-vmcnt pipeline (T3+T4): while computing
// K-tile t, stage tile t+3 into the buffer of dead tile t-1 (always cold).
// vmcnt(8) once per tile -> 2 tiles (64 KB) of staging always in flight,
// never drained to 0 in the main loop.  T2 chunk-XOR swizzle q^((row>>1)&3)
// gives uniform 8/bank spread on ds_read_b128 at the 64 B row pitch.
// T5 setprio around each 16-MFMA cluster.  Grid 8x32 = 256 blocks = 1/CU.
// ---------------------------------------------------------------------------
__device__ __forceinline__ bf16x8_t frag_ld(const __hip_bfloat16* buf, int row, int qd) {
    const int p = qd ^ ((row >> 1) & 3);
    return *(const bf16x8_t*)(buf + row * 32 + p * 8);
}

// Stage one 8 KB region: 128 rows x 32 bf16 cols, 512 threads x 16B.
// LDS dest is linear (wave-uniform base); the chunk swizzle is applied to the
// GLOBAL source address (both-sides-or-neither rule, m173/m201 pattern).
__device__ __forceinline__ void stage_call(const __hip_bfloat16* __restrict__ G,
                                           int grow0,               // global row of region start
                                           __hip_bfloat16* region,  // LDS tile base (row 0)
                                           int lrow0,               // region start row in tile (0/128)
                                           int w, int l, int k0) {
    const int rr   = w * 16 + (l >> 2);        // row within region 0..127
    const int lrow = lrow0 + rr;               // row within 256-row tile (swizzle key)
    const int kc   = (l & 3) ^ ((lrow >> 1) & 3);
    load_lds16(G + (size_t)(grow0 + rr) * K_DIM + k0 + kc * 8,
               (void*)(region + (size_t)(lrow0 + w * 16) * 32));  // wave-uniform
}

__global__ void __launch_bounds__(512, 2)
gemm256_kernel(const __hip_bfloat16* __restrict__ A,   // [M][K] = xs
               const __hip_bfloat16* __restrict__ B,   // [N][K] = W_eff
               const float* __restrict__ bias,         // [N]
               __hip_bfloat16* __restrict__ Cc)        // [M][N] compact
{
    __shared__ __hip_bfloat16 lds[4][2][256 * 32];     // [buf][A=0/B=1] 128 KiB

    const int tid = threadIdx.x;
    const int w   = tid >> 6;        // wave 0..7
    const int l   = tid & 63;
    const int r15 = l & 15;
    const int qd  = l >> 4;
    const int wm  = w >> 2;          // 0..1  (M half: 128 rows)
    const int wn  = w & 3;           // 0..3  (N quarter: 64 cols)
    const int m0  = blockIdx.y * 256;
    const int n0  = blockIdx.x * 256;

    f32x4_t acc[8][4] = {};

    // Prologue: stage K-tiles 0,1,2 (12 vmem instrs/wave).
    #pragma unroll
    for (int t = 0; t < 3; ++t) {
        const int k0 = t * 32;
        stage_call(A, m0,       lds[t][0], 0,   w, l, k0);
        stage_call(A, m0 + 128, lds[t][0], 128, w, l, k0);
        stage_call(B, n0,       lds[t][1], 0,   w, l, k0);
        stage_call(B, n0 + 128, lds[t][1], 128, w, l, k0);
    }
    asm volatile("s_waitcnt vmcnt(8)" ::: "memory");   // tile 0 landed; 1,2 in flight
    __builtin_amdgcn_sched_barrier(0);
    __builtin_amdgcn_s_barrier();

    // Main loop: 64 K-tiles of 32.  Stage index wraps (garbage into dead,
    // never-read buffers for t+3 >= 64) so vmcnt bookkeeping stays uniform.
    for (int tt = 0; tt < 64; tt += 4) {
        #pragma unroll
        for (int c = 0; c < 4; ++c) {
            const int bs  = c;                 // compute buffer (tt%4==0)
            const int bt  = (c + 3) & 3;       // stage target = dead t-1 buffer
            const int k0s = ((tt + c + 3) & 63) * 32;
            const __hip_bfloat16* Ab = lds[bs][0];
            const __hip_bfloat16* Bb = lds[bs][1];

            bf16x8_t af[4], bfr[4];
            // ---- phase 0: A rows [wm*128, +63], all B; stage next A ----
            #pragma unroll
            for (int i = 0; i < 4; ++i)
                af[i] = frag_ld(Ab, wm * 128 + i * 16 + r15, qd);
            #pragma unroll
            for (int j = 0; j < 4; ++j)
                bfr[j] = frag_ld(Bb, wn * 64 + j * 16 + r15, qd);
            stage_call(A, m0,       lds[bt][0], 0,   w, l, k0s);
            stage_call(A, m0 + 128, lds[bt][0], 128, w, l, k0s);
            __builtin_amdgcn_s_barrier();
            __builtin_amdgcn_s_setprio(1);
            #pragma unroll
            for (int i = 0; i < 4; ++i)
                #pragma unroll
                for (int j = 0; j < 4; ++j)
                    acc[i][j] = __builtin_amdgcn_mfma_f32_16x16x32_bf16(
                        af[i], bfr[j], acc[i][j], 0, 0, 0);
            __builtin_amdgcn_s_setprio(0);

            // ---- phase 1: A rows [wm*128+64, +63] (B reused); stage next B ----
            #pragma unroll
            for (int i = 0; i < 4; ++i)
                af[i] = frag_ld(Ab, wm * 128 + (4 + i) * 16 + r15, qd);
            stage_call(B, n0,       lds[bt][1], 0,   w, l, k0s);
            stage_call(B, n0 + 128, lds[bt][1], 128, w, l, k0s);
            __builtin_amdgcn_s_barrier();
            __builtin_amdgcn_s_setprio(1);
            #pragma unroll
            for (int i = 0; i < 4; ++i)
                #pragma unroll
                for (int j = 0; j < 4; ++j)
                    acc[4 + i][j] = __builtin_amdgcn_mfma_f32_16x16x32_bf16(
                        af[i], bfr[j], acc[4 + i][j], 0, 0, 0);
            __builtin_amdgcn_s_setprio(0);
            // Counted wait: keep 8 stage instrs (tiles t+2,t+3) in flight;
            // guarantees tile t+1 has landed before next iteration reads it.
            asm volatile("s_waitcnt vmcnt(8)" ::: "memory");
            __builtin_amdgcn_sched_barrier(0);
            __builtin_amdgcn_s_barrier();
        }
    }
    // Drain outstanding LDS-DMA before endpgm (LDS may be reassigned).
    asm volatile("s_waitcnt vmcnt(0)" ::: "memory");

    // Epilogue: C/D layout (verified m89/m91): col = lane&15, row = qd*4 + reg
    #pragma unroll
    for (int j = 0; j < 4; ++j) {
        const int gn = n0 + wn * 64 + j * 16 + r15;
        const float bv = bias[gn];
        #pragma unroll
        for (int i = 0; i < 8; ++i) {
            const int gm = m0 + wm * 128 + i * 16 + qd * 4;
            #pragma unroll
            for (int r = 0; r < 4; ++r)
                Cc[(size_t)(gm + r) * N_DIM + gn] =
                    __float2bfloat16(acc[i][j][r] + bv);
        }
    }
}

// ---------------------------------------------------------------------------
// Fallback GEMM (128x128, ws-too-small path) — unchanged from prior round.
// ---------------------------------------------------------------------------
template <bool COMPACT>
__global__ void __launch_bounds__(256, 2)
gemm_kernel(const __hip_bfloat16* __restrict__ A,
            const __hip_bfloat16* __restrict__ B,
            const float* __restrict__ bias,
            const int* __restrict__ oidx,
            float* __restrict__ out,
            __hip_bfloat16* __restrict__ Cc)
{
    __shared__ __hip_bfloat16 As[128 * 64];
    __shared__ __hip_bfloat16 Bs[128 * 64];

    const int tid  = threadIdx.x;
    const int wave = tid >> 6;
    const int lane = tid & 63;
    const int m0 = blockIdx.y * 128;
    const int n0 = blockIdx.x * 128;

    const int wm = (wave >> 1) * 64;
    const int wn = (wave & 1) * 64;

    const int srow  = tid >> 3;
    const int sslot = tid & 7;

    const int r15 = lane & 15;
    const int qd  = lane >> 4;

    f32x4_t acc[4][4] = {};

    for (int k0 = 0; k0 < K_DIM; k0 += 64) {
        #pragma unroll
        for (int it = 0; it < 4; ++it) {
            const int row = it * 32 + srow;
            const int q = sslot ^ (row & 7);
            const __hip_bfloat16* ga = A + (size_t)(m0 + row) * K_DIM + k0 + q * 8;
            const __hip_bfloat16* gb = B + (size_t)(n0 + row) * K_DIM + k0 + q * 8;
            load_lds16(ga, (void*)&As[(it * 32 + wave * 8) * 64]);
            load_lds16(gb, (void*)&Bs[(it * 32 + wave * 8) * 64]);
        }
        __syncthreads();

        #pragma unroll
        for (int s = 0; s < 2; ++s) {
            bf16x8_t af[4], bfr[4];
            #pragma unroll
            for (int i = 0; i < 4; ++i) {
                const int rowa = wm + i * 16 + r15;
                const int pa = (s * 4 + qd) ^ (rowa & 7);
                af[i] = *(const bf16x8_t*)&As[rowa * 64 + pa * 8];
                const int rowb = wn + i * 16 + r15;
                const int pb = (s * 4 + qd) ^ (rowb & 7);
                bfr[i] = *(const bf16x8_t*)&Bs[rowb * 64 + pb * 8];
            }
            #pragma unroll
            for (int i = 0; i < 4; ++i)
                #pragma unroll
                for (int j = 0; j < 4; ++j)
                    acc[i][j] = __builtin_amdgcn_mfma_f32_16x16x32_bf16(
                        af[i], bfr[j], acc[i][j], 0, 0, 0);
        }
        __syncthreads();
    }

    #pragma unroll
    for (int j = 0; j < 4; ++j) {
        const int gn = n0 + wn + j * 16 + r15;
        const float bv = bias[gn];
        if (COMPACT) {
            #pragma unroll
            for (int i = 0; i < 4; ++i) {
                const int gm = m0 + wm + i * 16 + qd * 4;
                #pragma unroll
                for (int r = 0; r < 4; ++r)
                    Cc[(size_t)(gm + r) * N_DIM + gn] =
                        __float2bfloat16(acc[i][j][r] + bv);
            }
        } else {
            const int oc = oidx[gn];
            #pragma unroll
            for (int i = 0; i < 4; ++i) {
                const int gm = m0 + wm + i * 16 + qd * 4;
                #pragma unroll
                for (int r = 0; r < 4; ++r)
                    out[(size_t)(gm + r) * OUT_DIM + oc] = acc[i][j][r] + bv;
            }
        }
    }
}

// ---------------------------------------------------------------------------
// Kernel 5: expand compact C into full output (zeros for unselected cols).
// ---------------------------------------------------------------------------
__global__ void __launch_bounds__(256)
scatter_out_kernel(const __hip_bfloat16* __restrict__ C,   // [M][N]
                   const int* __restrict__ inv,            // [OUT_DIM]
                   float* __restrict__ out) {              // [M][OUT_DIM]
    const int row = blockIdx.y;
    const int c0 = (blockIdx.x * 256 + threadIdx.x) * 4;
    const __hip_bfloat16* crow = C + (size_t)row * N_DIM;
    const int4 iv = *(const int4*)(inv + c0);
    float4 v;
    v.x = (iv.x >= 0) ? __bfloat162float(crow[iv.x]) : 0.0f;
    v.y = (iv.y >= 0) ? __bfloat162float(crow[iv.y]) : 0.0f;
    v.z = (iv.z >= 0) ? __bfloat162float(crow[iv.z]) : 0.0f;
    v.w = (iv.w >= 0) ? __bfloat162float(crow[iv.w]) : 0.0f;
    *(float4*)(out + (size_t)row * OUT_DIM + c0) = v;
}

// ---------------------------------------------------------------------------
extern "C" void kernel_launch(void* const* d_in, const int* in_sizes, int n_in,
                              void* d_out, int out_size, void* d_ws, size_t ws_size,
                              hipStream_t stream) {
    const float* x      = (const float*)d_in[0];   // [2,4096,4096]
    const float* W_base = (const float*)d_in[1];   // [2048,2048]
    const float* b_base = (const float*)d_in[2];   // [2048]
    const float* lora_A = (const float*)d_in[3];   // [16,2048]
    const float* lora_B = (const float*)d_in[4];   // [2048,16]
    const int* in_idx   = (const int*)d_in[5];     // [2048]
    const int* out_idx  = (const int*)d_in[6];     // [2048]
    float* out = (float*)d_out;                    // [8192,4096]

    const size_t sz_xs = (size_t)M_DIM * K_DIM * 2;   // 32 MB
    const size_t sz_We = (size_t)N_DIM * K_DIM * 2;   //  8 MB
    const size_t sz_C  = (size_t)M_DIM * N_DIM * 2;   // 32 MB
    const size_t sz_inv = (size_t)OUT_DIM * 4;        // 16 KB

    __hip_bfloat16* xs = (__hip_bfloat16*)d_ws;
    __hip_bfloat16* We = (__hip_bfloat16*)((char*)d_ws + sz_xs);
    __hip_bfloat16* Cc = (__hip_bfloat16*)((char*)d_ws + sz_xs + sz_We);
    int* inv           = (int*)((char*)d_ws + sz_xs + sz_We + sz_C);

    fold_w_kernel<<<dim3(K_DIM / 256, N_DIM), 256, 0, stream>>>(W_base, lora_A, lora_B, We);
    gather_cast_kernel<<<M_DIM, 256, 0, stream>>>(x, in_idx, xs);

    if (ws_size >= sz_xs + sz_We + sz_C + sz_inv) {
        // Compact path: 256^2 quad-buffered pipelined GEMM -> bf16 C,
        // then coalesced expand (no memset).
        build_inv_kernel<<<OUT_DIM / 256, 256, 0, stream>>>(out_idx, inv);
        gemm256_kernel<<<dim3(N_DIM / 256, M_DIM / 256), 512, 0, stream>>>(
            xs, We, b_base, Cc);
        scatter_out_kernel<<<dim3(OUT_DIM / (256 * 4), M_DIM), 256, 0, stream>>>(
            Cc, inv, out);
    } else {
        // Fallback: memset + scattered epilogue (128^2 GEMM).
        hipMemsetAsync(d_out, 0, (size_t)M_DIM * OUT_DIM * sizeof(float), stream);
        gemm_kernel<false><<<dim3(N_DIM / 128, M_DIM / 128), 256, 0, stream>>>(
            xs, We, b_base, out_idx, out, Cc);
    }
}